// Round 1
// baseline (314.553 us; speedup 1.0000x reference)
//
#include <hip/hip_runtime.h>
#include <hip/hip_bf16.h>

#define N 8192
#define D 64

typedef __attribute__((ext_vector_type(8))) short bf16x8;
typedef __attribute__((ext_vector_type(4))) float f32x4;

__device__ inline unsigned short f2b(float f) {
    __hip_bfloat16 h = __float2bfloat16(f);
    return __builtin_bit_cast(unsigned short, h);
}

// Kernel 1: convert X (fp32) -> Xb (bf16), compute sq[i] = ||x_i||^2.
// 512 blocks x 256 threads, each thread handles one float4 (4 elements).
__global__ __launch_bounds__(256) void gk_prep(const float4* __restrict__ X4,
                                               ushort4* __restrict__ Xb4,
                                               float* __restrict__ sq) {
    const int g = blockIdx.x * 256 + threadIdx.x;   // float4 index, [0, 131072)
    float4 v = X4[g];
    ushort4 b;
    b.x = f2b(v.x); b.y = f2b(v.y); b.z = f2b(v.z); b.w = f2b(v.w);
    Xb4[g] = b;
    float ss = v.x * v.x + v.y * v.y + v.z * v.z + v.w * v.w;
    // 16 consecutive threads cover one row (16 x float4 = 64 elems)
    ss += __shfl_xor(ss, 8, 16);
    ss += __shfl_xor(ss, 4, 16);
    ss += __shfl_xor(ss, 2, 16);
    ss += __shfl_xor(ss, 1, 16);
    if ((threadIdx.x & 15) == 0) sq[g >> 4] = ss;
}

// Kernel 2: V[c] = sum_r X[r][c]. One block per column.
__global__ __launch_bounds__(256) void gk_colsum(const float* __restrict__ X,
                                                 float* __restrict__ V) {
    __shared__ float red[256];
    const int c = blockIdx.x;
    float s = 0.f;
    for (int r = threadIdx.x; r < N; r += 256) s += X[r * D + c];
    red[threadIdx.x] = s;
    __syncthreads();
    for (int off = 128; off > 0; off >>= 1) {
        if (threadIdx.x < off) red[threadIdx.x] += red[threadIdx.x + off];
        __syncthreads();
    }
    if (threadIdx.x == 0) V[c] = red[0];
}

// Kernel 3: S = sum(sq), Vsq = ||V||^2; mean(d2) = 2S/N - 2Vsq/N^2;
// c0 = 1/(2*ALPHA*mean). One block.
__global__ __launch_bounds__(256) void gk_finalize(const float* __restrict__ sq,
                                                   const float* __restrict__ V,
                                                   float* __restrict__ scal) {
    __shared__ float red[256];
    float s = 0.f;
    for (int r = threadIdx.x; r < N; r += 256) s += sq[r];
    red[threadIdx.x] = s;
    __syncthreads();
    for (int off = 128; off > 0; off >>= 1) {
        if (threadIdx.x < off) red[threadIdx.x] += red[threadIdx.x + off];
        __syncthreads();
    }
    const float S = red[0];
    __syncthreads();
    float v = (threadIdx.x < D) ? V[threadIdx.x] : 0.f;
    red[threadIdx.x] = v * v;
    __syncthreads();
    for (int off = 128; off > 0; off >>= 1) {
        if (threadIdx.x < off) red[threadIdx.x] += red[threadIdx.x + off];
        __syncthreads();
    }
    if (threadIdx.x == 0) {
        const float Vsq = red[0];
        const float fN = (float)N;
        const float mean = 2.f * S / fN - 2.f * Vsq / (fN * fN);
        const float sigma_sq = 1.0f * mean;   // ALPHA = 1.0
        scal[0] = 1.f / (2.f * sigma_sq);
    }
}

// Kernel 4: main. Block tile 64 rows x 128 cols; 4 waves, each 16 rows x 128 cols.
// mfma_f32_16x16x32_bf16, K=64 -> 2 MFMAs per 16x16 tile.
// A-frag (lane l): row = i0 + (l&15), k = 8*(l>>4) + j, j=0..7 (contig bf16x8)
// B-frag (lane l): col = j0 + (l&15), same k pattern (B = X^T so same load shape)
// C/D (lane l, reg r): col = l&15, row = 4*(l>>4) + r   [guide §3, m89-verified]
__global__ __launch_bounds__(256) void gk_main(const unsigned short* __restrict__ Xb,
                                               const float* __restrict__ sq,
                                               const float* __restrict__ scal,
                                               float* __restrict__ out) {
    const int lane = threadIdx.x & 63;
    const int wave = threadIdx.x >> 6;
    const int i0 = blockIdx.x * 64 + wave * 16;
    const int j0 = blockIdx.y * 128;
    const int m = lane & 15;
    const int q = lane >> 4;   // 0..3
    const float c0 = scal[0];

    // A fragments: elems (i0+m)*64 + 8q (+32 for k-chunk 1). bf16x8 = 8 elems = 16B.
    const bf16x8* Arow = reinterpret_cast<const bf16x8*>(Xb + (i0 + m) * D + 8 * q);
    const bf16x8 a0 = Arow[0];   // k in [8q, 8q+8)
    const bf16x8 a1 = Arow[4];   // k in [32+8q, 32+8q+8)

    f32x4 acc[8];
#pragma unroll
    for (int t = 0; t < 8; ++t) acc[t] = (f32x4){0.f, 0.f, 0.f, 0.f};

#pragma unroll
    for (int t = 0; t < 8; ++t) {
        const bf16x8* Brow =
            reinterpret_cast<const bf16x8*>(Xb + (j0 + t * 16 + m) * D + 8 * q);
        const bf16x8 b0 = Brow[0];
        const bf16x8 b1 = Brow[4];
        acc[t] = __builtin_amdgcn_mfma_f32_16x16x32_bf16(a0, b0, acc[t], 0, 0, 0);
        acc[t] = __builtin_amdgcn_mfma_f32_16x16x32_bf16(a1, b1, acc[t], 0, 0, 0);
    }

    float sqi[4];
#pragma unroll
    for (int r = 0; r < 4; ++r) sqi[r] = sq[i0 + 4 * q + r];

#pragma unroll
    for (int t = 0; t < 8; ++t) {
        const int col = j0 + t * 16 + m;
        const float sqj = sq[col];
#pragma unroll
        for (int r = 0; r < 4; ++r) {
            float d2 = sqi[r] + sqj - 2.0f * acc[t][r];
            d2 = fmaxf(d2, 0.0f);
            out[(size_t)(i0 + 4 * q + r) * N + col] = __expf(-d2 * c0);
        }
    }
}

extern "C" void kernel_launch(void* const* d_in, const int* in_sizes, int n_in,
                              void* d_out, int out_size, void* d_ws, size_t ws_size,
                              hipStream_t stream) {
    const float* X = (const float*)d_in[0];
    float* out = (float*)d_out;

    char* ws = (char*)d_ws;
    unsigned short* Xb = (unsigned short*)ws;                    // 8192*64*2 = 1 MiB
    float* sq = (float*)(ws + 1048576);                          // 32 KiB
    float* V  = (float*)(ws + 1048576 + 32768);                  // 256 B
    float* scal = (float*)(ws + 1048576 + 32768 + 256);          // scalars

    gk_prep<<<512, 256, 0, stream>>>((const float4*)X, (ushort4*)Xb, sq);
    gk_colsum<<<D, 256, 0, stream>>>(X, V);
    gk_finalize<<<1, 256, 0, stream>>>(sq, V, scal);

    dim3 grid(N / 64, N / 128);   // 128 x 64 blocks
    gk_main<<<grid, 256, 0, stream>>>(Xb, sq, scal, out);
}